// Round 3
// baseline (685.347 us; speedup 1.0000x reference)
//
#include <hip/hip_runtime.h>

#define N_NODES 50000
#define E_EDGES 800000
#define DIN 128
#define DOUT 64
#define BSH 6                       // bucket = row >> 6 (64 rows/bucket)
#define NB 782                      // 782 * 64 = 50048 >= N_NODES

// ---------------- K1: fused L2norm + BN(eval) + Linear -> X [N,64] ----------
__global__ __launch_bounds__(256) void k_x(
    const float* __restrict__ H, const float* __restrict__ gamma,
    const float* __restrict__ beta, const float* __restrict__ mean,
    const float* __restrict__ var, const float* __restrict__ W,
    const float* __restrict__ bias, float* __restrict__ X, int iters)
{
    __shared__ float s_hb[4][DIN];
    const int lane = threadIdx.x & 63;
    const int wv   = threadIdx.x >> 6;

    float w[DIN];
#pragma unroll
    for (int k = 0; k < DIN; ++k) w[k] = W[k * DOUT + lane];
    const float bj = bias[lane];

    const int k0 = lane * 2;
    const float2 g  = *(const float2*)(gamma + k0);
    const float2 be = *(const float2*)(beta  + k0);
    const float2 mn = *(const float2*)(mean  + k0);
    const float2 vr = *(const float2*)(var   + k0);
    const float sc0 = g.x / sqrtf(vr.x + 1e-5f);
    const float sc1 = g.y / sqrtf(vr.y + 1e-5f);
    const float sh0 = be.x - mn.x * sc0;
    const float sh1 = be.y - mn.y * sc1;

    for (int it = 0; it < iters; ++it) {
        const int row = (it * gridDim.x + blockIdx.x) * 4 + wv;
        const bool act = row < N_NODES;
        float2 h = make_float2(0.f, 0.f);
        if (act) h = *(const float2*)(H + (size_t)row * DIN + k0);

        float ss = h.x * h.x + h.y * h.y;
#pragma unroll
        for (int o = 32; o > 0; o >>= 1) ss += __shfl_xor(ss, o, 64);
        const float inv = 1.0f / fmaxf(sqrtf(ss), 1e-12f);

        s_hb[wv][k0]     = h.x * inv * sc0 + sh0;
        s_hb[wv][k0 + 1] = h.y * inv * sc1 + sh1;
        __syncthreads();

        float a0 = bj, a1 = 0.f;
#pragma unroll
        for (int k = 0; k < DIN; k += 4) {
            const float4 hb = *(const float4*)&s_hb[wv][k];
            a0 = fmaf(hb.x, w[k],     a0);
            a1 = fmaf(hb.y, w[k + 1], a1);
            a0 = fmaf(hb.z, w[k + 2], a0);
            a1 = fmaf(hb.w, w[k + 3], a1);
        }
        if (act) X[(size_t)row * DOUT + lane] = a0 + a1;
        __syncthreads();
    }
}

// ---------------- K2: bucket histogram via LDS ------------------------------
// 196 blocks x 1024 threads, 4 edges/thread; one global atomic per (block,bin).
__global__ __launch_bounds__(1024) void k_bcount(
    const int* __restrict__ rows, int* __restrict__ hist)
{
    __shared__ int lh[NB];
    const int t = threadIdx.x;
    if (t < NB) lh[t] = 0;
    __syncthreads();
    const int e0 = blockIdx.x * 4096;
#pragma unroll
    for (int k = 0; k < 4; ++k) {
        const int e = e0 + k * 1024 + t;
        if (e < E_EDGES) atomicAdd(&lh[rows[e] >> BSH], 1);
    }
    __syncthreads();
    if (t < NB) {
        const int c = lh[t];
        if (c) atomicAdd(&hist[t], c);
    }
}

// ---------------- K3: scan of 782 bucket counts (single block) --------------
__global__ __launch_bounds__(1024) void k_bscan(
    const int* __restrict__ hist, int* __restrict__ bstart, int* __restrict__ bcursor)
{
    const int t = threadIdx.x;
    const int lane = t & 63, wv = t >> 6;
    const int v = (t < NB) ? hist[t] : 0;
    int x = v;
#pragma unroll
    for (int o = 1; o < 64; o <<= 1) {
        const int y = __shfl_up(x, o, 64);
        if (lane >= o) x += y;
    }
    __shared__ int wsum[16];
    if (lane == 63) wsum[wv] = x;
    __syncthreads();
    int pre = 0;
    for (int i = 0; i < wv; ++i) pre += wsum[i];
    const int ex = pre + x - v;       // exclusive prefix
    if (t < NB) { bstart[t] = ex; bcursor[t] = ex; }
    if (t == NB) bstart[NB] = ex;     // == E
}

// ---------------- K4: scatter edges into bucket windows ---------------------
// pack: col (16 bits, N<65536) | lrow (6 bits) << 16
__global__ void k_bscatter(const int* __restrict__ rows, const int* __restrict__ cols,
                           const float* __restrict__ vals, int* __restrict__ bcursor,
                           uint2* __restrict__ ev)
{
    const int e = blockIdx.x * blockDim.x + threadIdx.x;
    if (e < E_EDGES) {
        const int r = rows[e];
        const int b = r >> BSH;
        const int pos = atomicAdd(&bcursor[b], 1);
        const unsigned pack = (unsigned)cols[e] | ((unsigned)(r & 63) << 16);
        ev[pos] = make_uint2(__float_as_uint(vals[e]), pack);
    }
}

// ---------------- K5: bucket SpMM + LeakyReLU (LDS accumulator) -------------
__global__ __launch_bounds__(256) void k_bspmm(
    const int* __restrict__ bstart, const uint2* __restrict__ ev,
    const float* __restrict__ X, float* __restrict__ out)
{
    __shared__ float acc[64 * 64];
    const int b    = blockIdx.x;
    const int t    = threadIdx.x;
    const int lane = t & 63;
    const int wv   = t >> 6;

    float4* accv = (float4*)acc;
#pragma unroll
    for (int i = t; i < 1024; i += 256) accv[i] = make_float4(0.f, 0.f, 0.f, 0.f);
    __syncthreads();

    const int s  = bstart[b];
    const int e2 = bstart[b + 1];
    for (int base = s + wv * 64; base < e2; base += 256) {
        const int idx = base + lane;
        uint2 p = make_uint2(0u, 0u);
        if (idx < e2) p = ev[idx];
        const int cnt = min(e2 - base, 64);
        int j = 0;
        for (; j + 3 < cnt; j += 4) {
            const float v0 = __uint_as_float(__shfl((int)p.x, j,     64));
            const int  pk0 = __shfl((int)p.y, j,     64);
            const float v1 = __uint_as_float(__shfl((int)p.x, j + 1, 64));
            const int  pk1 = __shfl((int)p.y, j + 1, 64);
            const float v2 = __uint_as_float(__shfl((int)p.x, j + 2, 64));
            const int  pk2 = __shfl((int)p.y, j + 2, 64);
            const float v3 = __uint_as_float(__shfl((int)p.x, j + 3, 64));
            const int  pk3 = __shfl((int)p.y, j + 3, 64);
            const float x0 = X[(size_t)(pk0 & 0xFFFF) * DOUT + lane];
            const float x1 = X[(size_t)(pk1 & 0xFFFF) * DOUT + lane];
            const float x2 = X[(size_t)(pk2 & 0xFFFF) * DOUT + lane];
            const float x3 = X[(size_t)(pk3 & 0xFFFF) * DOUT + lane];
            atomicAdd(&acc[((pk0 >> 16) & 63) * 64 + lane], v0 * x0);
            atomicAdd(&acc[((pk1 >> 16) & 63) * 64 + lane], v1 * x1);
            atomicAdd(&acc[((pk2 >> 16) & 63) * 64 + lane], v2 * x2);
            atomicAdd(&acc[((pk3 >> 16) & 63) * 64 + lane], v3 * x3);
        }
        for (; j < cnt; ++j) {
            const float v = __uint_as_float(__shfl((int)p.x, j, 64));
            const int  pk = __shfl((int)p.y, j, 64);
            const float x = X[(size_t)(pk & 0xFFFF) * DOUT + lane];
            atomicAdd(&acc[((pk >> 16) & 63) * 64 + lane], v * x);
        }
    }
    __syncthreads();

    const int r0 = b << BSH;
#pragma unroll
    for (int i = 0; i < 4; ++i) {
        const int off = (i * 256 + t) * 4;       // 0..4095, 16B aligned
        const int row = off >> 6, col = off & 63;
        if (r0 + row < N_NODES) {
            float4 a = *(float4*)&acc[off];
            a.x = (a.x >= 0.f) ? a.x : 0.01f * a.x;
            a.y = (a.y >= 0.f) ? a.y : 0.01f * a.y;
            a.z = (a.z >= 0.f) ? a.z : 0.01f * a.z;
            a.w = (a.w >= 0.f) ? a.w : 0.01f * a.w;
            *(float4*)(out + (size_t)(r0 + row) * DOUT + col) = a;
        }
    }
}

extern "C" void kernel_launch(void* const* d_in, const int* in_sizes, int n_in,
                              void* d_out, int out_size, void* d_ws, size_t ws_size,
                              hipStream_t stream)
{
    const float* H     = (const float*)d_in[0];
    const int*   rows  = (const int*)  d_in[1];
    const int*   cols  = (const int*)  d_in[2];
    const float* vals  = (const float*)d_in[3];
    const float* gamma = (const float*)d_in[4];
    const float* beta  = (const float*)d_in[5];
    const float* mean  = (const float*)d_in[6];
    const float* var   = (const float*)d_in[7];
    const float* W     = (const float*)d_in[8];
    const float* bias  = (const float*)d_in[9];
    float* out = (float*)d_out;

    char* ws = (char*)d_ws;
    float* X       = (float*)(ws);                    // 12,800,000 B
    int*   hist    = (int*)  (ws + 12800000);         // 3,128 B
    int*   bstart  = (int*)  (ws + 12803200);         // 3,132 B
    int*   bcursor = (int*)  (ws + 12806400);         // 3,128 B
    uint2* ev      = (uint2*)(ws + 12809600);         // 6,400,000 B

    hipMemsetAsync(hist, 0, NB * sizeof(int), stream);

    const int gridx = 1024;
    const int iters = (N_NODES + gridx * 4 - 1) / (gridx * 4);
    k_x<<<gridx, 256, 0, stream>>>(H, gamma, beta, mean, var, W, bias, X, iters);
    k_bcount<<<196, 1024, 0, stream>>>(rows, hist);
    k_bscan<<<1, 1024, 0, stream>>>(hist, bstart, bcursor);
    k_bscatter<<<(E_EDGES + 255) / 256, 256, 0, stream>>>(rows, cols, vals, bcursor, ev);
    k_bspmm<<<NB, 256, 0, stream>>>(bstart, ev, X, out);
}

// Round 4
// 184.826 us; speedup vs baseline: 3.7081x; 3.7081x over previous
//
#include <hip/hip_runtime.h>

#define N_NODES 50000
#define E_EDGES 800000
#define DIN 128
#define DOUT 64
#define NBUK 196            // bucket = row >> 8; 196*256 = 50176 >= N
#define CHUNK 4096          // edges per pass-A block
#define NBLKA 196           // ceil(E/CHUNK)

// ---------------- K1: fused L2norm + BN(eval) + Linear -> X [N,64] ----------
__global__ __launch_bounds__(256) void k_x(
    const float* __restrict__ H, const float* __restrict__ gamma,
    const float* __restrict__ beta, const float* __restrict__ mean,
    const float* __restrict__ var, const float* __restrict__ W,
    const float* __restrict__ bias, float* __restrict__ X, int iters)
{
    __shared__ float s_hb[4][DIN];
    const int lane = threadIdx.x & 63;
    const int wv   = threadIdx.x >> 6;

    float w[DIN];
#pragma unroll
    for (int k = 0; k < DIN; ++k) w[k] = W[k * DOUT + lane];
    const float bj = bias[lane];

    const int k0 = lane * 2;
    const float2 g  = *(const float2*)(gamma + k0);
    const float2 be = *(const float2*)(beta  + k0);
    const float2 mn = *(const float2*)(mean  + k0);
    const float2 vr = *(const float2*)(var   + k0);
    const float sc0 = g.x / sqrtf(vr.x + 1e-5f);
    const float sc1 = g.y / sqrtf(vr.y + 1e-5f);
    const float sh0 = be.x - mn.x * sc0;
    const float sh1 = be.y - mn.y * sc1;

    for (int it = 0; it < iters; ++it) {
        const int row = (it * gridDim.x + blockIdx.x) * 4 + wv;
        const bool act = row < N_NODES;
        float2 h = make_float2(0.f, 0.f);
        if (act) h = *(const float2*)(H + (size_t)row * DIN + k0);

        float ss = h.x * h.x + h.y * h.y;
#pragma unroll
        for (int o = 32; o > 0; o >>= 1) ss += __shfl_xor(ss, o, 64);
        const float inv = 1.0f / fmaxf(sqrtf(ss), 1e-12f);

        s_hb[wv][k0]     = h.x * inv * sc0 + sh0;
        s_hb[wv][k0 + 1] = h.y * inv * sc1 + sh1;
        __syncthreads();

        float a0 = bj, a1 = 0.f;
#pragma unroll
        for (int k = 0; k < DIN; k += 4) {
            const float4 hb = *(const float4*)&s_hb[wv][k];
            a0 = fmaf(hb.x, w[k],     a0);
            a1 = fmaf(hb.y, w[k + 1], a1);
            a0 = fmaf(hb.z, w[k + 2], a0);
            a1 = fmaf(hb.w, w[k + 3], a1);
        }
        if (act) X[(size_t)row * DOUT + lane] = a0 + a1;
        __syncthreads();
    }
}

// ---------------- K2: bucket histogram (196 bins) via LDS -------------------
__global__ __launch_bounds__(1024) void k_bhist(
    const int* __restrict__ rows, int* __restrict__ hist)
{
    __shared__ int lh[NBUK];
    const int t = threadIdx.x;
    if (t < NBUK) lh[t] = 0;
    __syncthreads();
    const int e0 = blockIdx.x * 8192;
#pragma unroll
    for (int k = 0; k < 8; ++k) {
        const int e = e0 + k * 1024 + t;
        if (e < E_EDGES) atomicAdd(&lh[rows[e] >> 8], 1);
    }
    __syncthreads();
    if (t < NBUK) {
        const int c = lh[t];
        if (c) atomicAdd(&hist[t], c);
    }
}

// ---------------- K3: scan 196 bucket counts (1 block) ----------------------
__global__ __launch_bounds__(256) void k_bscan(
    const int* __restrict__ hist, int* __restrict__ gstart, int* __restrict__ gcursor)
{
    __shared__ int sc[256];
    const int t = threadIdx.x;
    const int v = (t < NBUK) ? hist[t] : 0;
    sc[t] = v;
    __syncthreads();
    for (int o = 1; o < 256; o <<= 1) {
        const int u = (t >= o) ? sc[t - o] : 0;
        __syncthreads();
        sc[t] += u;
        __syncthreads();
    }
    const int ex = sc[t] - v;
    if (t < NBUK) { gstart[t] = ex; gcursor[t] = ex; }
    if (t == NBUK - 1) gstart[NBUK] = ex + v;   // == E
}

// ---------------- K4: pass A — LDS-staged scatter into bucket runs ----------
// pack: col(16b) | (row&255)<<16 | (row>>8)<<24
__global__ __launch_bounds__(256) void k_passA(
    const int* __restrict__ rows, const int* __restrict__ cols,
    const float* __restrict__ vals, int* __restrict__ gcursor,
    uint2* __restrict__ mid)
{
    __shared__ int lhist[NBUK], lstart[NBUK], lcur[NBUK], gbase[NBUK];
    __shared__ int sc[256];
    __shared__ uint2 lbin[CHUNK];
    const int t = threadIdx.x;
    const int e0 = blockIdx.x * CHUNK;
    const int nC = min(CHUNK, E_EDGES - e0);

    if (t < NBUK) lhist[t] = 0;
    __syncthreads();

    uint2 pr[16];
#pragma unroll
    for (int k = 0; k < 16; ++k) {
        const int e = e0 + k * 256 + t;
        if (e < E_EDGES) {
            const int r = rows[e];
            const unsigned pk = (unsigned)cols[e] | ((unsigned)(r & 255) << 16)
                              | ((unsigned)(r >> 8) << 24);
            pr[k] = make_uint2(__float_as_uint(vals[e]), pk);
            atomicAdd(&lhist[r >> 8], 1);
        } else {
            pr[k] = make_uint2(0u, 0xFFFFFFFFu);   // invalid (bucket 255 >= NBUK)
        }
    }
    __syncthreads();

    const int v = (t < NBUK) ? lhist[t] : 0;
    sc[t] = v;
    __syncthreads();
    for (int o = 1; o < 256; o <<= 1) {
        const int u = (t >= o) ? sc[t - o] : 0;
        __syncthreads();
        sc[t] += u;
        __syncthreads();
    }
    if (t < NBUK) {
        const int ex = sc[t] - v;
        lstart[t] = ex;
        lcur[t] = ex;
        gbase[t] = v ? atomicAdd(&gcursor[t], v) : 0;
    }
    __syncthreads();

#pragma unroll
    for (int k = 0; k < 16; ++k) {
        const unsigned pk = pr[k].y;
        if (pk != 0xFFFFFFFFu) {
            const int b = pk >> 24;
            const int pos = atomicAdd(&lcur[b], 1);
            lbin[pos] = pr[k];
        }
    }
    __syncthreads();

    for (int i = t; i < nC; i += 256) {
        const uint2 p = lbin[i];
        const int b = p.y >> 24;
        mid[gbase[b] + (i - lstart[b])] = p;
    }
}

// ---------------- K5: pass B — exact CSR within each bucket -----------------
__global__ __launch_bounds__(256) void k_passB(
    const int* __restrict__ gstart, const uint2* __restrict__ mid,
    uint2* __restrict__ ev, int* __restrict__ startRow)
{
    __shared__ int lhist[256], sc[256], lcur[256];
    const int t = threadIdx.x;
    const int b = blockIdx.x;
    const int s = gstart[b], e2 = gstart[b + 1];

    lhist[t] = 0;
    __syncthreads();
    for (int i = s + t; i < e2; i += 256)
        atomicAdd(&lhist[(mid[i].y >> 16) & 255], 1);
    __syncthreads();

    const int v = lhist[t];
    sc[t] = v;
    __syncthreads();
    for (int o = 1; o < 256; o <<= 1) {
        const int u = (t >= o) ? sc[t - o] : 0;
        __syncthreads();
        sc[t] += u;
        __syncthreads();
    }
    const int ex = sc[t] - v;
    lcur[t] = ex;
    const int gr = b * 256 + t;
    if (gr <= N_NODES) startRow[gr] = s + ex;   // start[N] written by last bucket
    __syncthreads();

    for (int i = s + t; i < e2; i += 256) {
        const uint2 p = mid[i];
        const int r8 = (p.y >> 16) & 255;
        const int pos = atomicAdd(&lcur[r8], 1);
        ev[s + pos] = make_uint2(p.x, p.y & 0xFFFFu);
    }
}

// ---------------- K6: row-centric SpMM + LeakyReLU (R2 structure) -----------
__global__ __launch_bounds__(256) void k_spmm(
    const int* __restrict__ start, const uint2* __restrict__ ev,
    const float* __restrict__ X, float* __restrict__ out)
{
    const int lane = threadIdx.x & 63;
    const int row  = blockIdx.x * 4 + (threadIdx.x >> 6);
    if (row >= N_NODES) return;
    const int s  = start[row];
    const int e2 = start[row + 1];
    float acc = 0.f;
    for (int c = s; c < e2; c += 64) {
        const int idx = c + lane;
        uint2 p = make_uint2(0u, 0u);
        if (idx < e2) p = ev[idx];
        const int cnt = min(e2 - c, 64);
        int j = 0;
        for (; j + 3 < cnt; j += 4) {
            const float v0 = __uint_as_float(__shfl((int)p.x, j,     64));
            const int   c0 = __shfl((int)p.y, j,     64);
            const float v1 = __uint_as_float(__shfl((int)p.x, j + 1, 64));
            const int   c1 = __shfl((int)p.y, j + 1, 64);
            const float v2 = __uint_as_float(__shfl((int)p.x, j + 2, 64));
            const int   c2 = __shfl((int)p.y, j + 2, 64);
            const float v3 = __uint_as_float(__shfl((int)p.x, j + 3, 64));
            const int   c3 = __shfl((int)p.y, j + 3, 64);
            const float x0 = X[(size_t)c0 * DOUT + lane];
            const float x1 = X[(size_t)c1 * DOUT + lane];
            const float x2 = X[(size_t)c2 * DOUT + lane];
            const float x3 = X[(size_t)c3 * DOUT + lane];
            acc = fmaf(v0, x0, acc);
            acc = fmaf(v1, x1, acc);
            acc = fmaf(v2, x2, acc);
            acc = fmaf(v3, x3, acc);
        }
        for (; j < cnt; ++j) {
            const float v  = __uint_as_float(__shfl((int)p.x, j, 64));
            const int col  = __shfl((int)p.y, j, 64);
            acc = fmaf(v, X[(size_t)col * DOUT + lane], acc);
        }
    }
    out[(size_t)row * DOUT + lane] = (acc >= 0.f) ? acc : 0.01f * acc;
}

extern "C" void kernel_launch(void* const* d_in, const int* in_sizes, int n_in,
                              void* d_out, int out_size, void* d_ws, size_t ws_size,
                              hipStream_t stream)
{
    const float* H     = (const float*)d_in[0];
    const int*   rows  = (const int*)  d_in[1];
    const int*   cols  = (const int*)  d_in[2];
    const float* vals  = (const float*)d_in[3];
    const float* gamma = (const float*)d_in[4];
    const float* beta  = (const float*)d_in[5];
    const float* mean  = (const float*)d_in[6];
    const float* var   = (const float*)d_in[7];
    const float* W     = (const float*)d_in[8];
    const float* bias  = (const float*)d_in[9];
    float* out = (float*)d_out;

    char* ws = (char*)d_ws;
    float* X        = (float*)(ws);                    // 12,800,000 B
    int*   hist     = (int*)  (ws + 12800000);         //        784 B
    int*   gstart   = (int*)  (ws + 12800800);         //        788 B
    int*   gcursor  = (int*)  (ws + 12801600);         //        784 B
    int*   startRow = (int*)  (ws + 12802400);         //    200,004 B
    uint2* mid      = (uint2*)(ws + 13002416);         //  6,400,000 B
    uint2* ev       = (uint2*)(ws + 19402416);         //  6,400,000 B

    hipMemsetAsync(hist, 0, NBUK * sizeof(int), stream);

    const int gridx = 1024;
    const int iters = (N_NODES + gridx * 4 - 1) / (gridx * 4);
    k_x<<<gridx, 256, 0, stream>>>(H, gamma, beta, mean, var, W, bias, X, iters);
    k_bhist<<<(E_EDGES + 8191) / 8192, 1024, 0, stream>>>(rows, hist);
    k_bscan<<<1, 256, 0, stream>>>(hist, gstart, gcursor);
    k_passA<<<NBLKA, 256, 0, stream>>>(rows, cols, vals, gcursor, mid);
    k_passB<<<NBUK, 256, 0, stream>>>(gstart, mid, ev, startRow);
    k_spmm<<<(N_NODES + 3) / 4, 256, 0, stream>>>(startRow, ev, X, out);
}

// Round 5
// 166.851 us; speedup vs baseline: 4.1075x; 1.1077x over previous
//
#include <hip/hip_runtime.h>

#define N_NODES 50000
#define E_EDGES 800000
#define DIN 128
#define DOUT 64
#define NBUK 196            // bucket = row >> 8; 196*256 = 50176 >= N
#define CHUNK 4096          // edges per pass-A block
#define NBLKA 196           // ceil(E/CHUNK)
#define ASTRIDE 136         // bf16 LDS row stride (272B = 17*16B, balanced banks)

typedef short short8 __attribute__((ext_vector_type(8)));
typedef float f32x4 __attribute__((ext_vector_type(4)));

static __device__ __forceinline__ short f2bf(float f)
{
    union { float f; unsigned u; } x{f};
    const unsigned r = x.u + 0x7FFFu + ((x.u >> 16) & 1u);   // RNE
    return (short)(r >> 16);
}

// ---------------- K0: one-time prep — W^T bf16, BN scale/shift --------------
__global__ void k_prep(const float* __restrict__ W, const float* __restrict__ gamma,
                       const float* __restrict__ beta, const float* __restrict__ mean,
                       const float* __restrict__ var,
                       unsigned short* __restrict__ Wt, float* __restrict__ sc,
                       float* __restrict__ sh)
{
    const int idx = blockIdx.x * 256 + threadIdx.x;      // 8192 threads
    const int n = idx >> 7, k = idx & 127;
    Wt[n * DIN + k] = (unsigned short)f2bf(W[k * DOUT + n]);
    if (idx < DIN) {
        const float s = gamma[idx] / sqrtf(var[idx] + 1e-5f);
        sc[idx] = s;
        sh[idx] = beta[idx] - mean[idx] * s;
    }
}

// ---------------- K1: fused L2norm + BN + Linear via bf16 MFMA --------------
// block = 256 (4 waves) handles 64 rows. A-tile (hb, bf16) and B-tile (W^T
// bf16) staged in LDS; 16x16x32 MFMA; bias in acc init; fp32 X out.
__global__ __launch_bounds__(256) void k_x(
    const float* __restrict__ H, const float* __restrict__ sc,
    const float* __restrict__ sh, const unsigned short* __restrict__ Wt,
    const float* __restrict__ bias, float* __restrict__ X)
{
    __shared__ short A_s[64][ASTRIDE];
    __shared__ short B_s[64][ASTRIDE];
    const int t = threadIdx.x;
    const int l = t & 63, wv = t >> 6;
    const int R0 = blockIdx.x * 64;

    // ---- stage A: 4 threads per row, 32 k's per thread ----
    {
        const int rloc = t >> 2, sub = t & 3;
        const int r = R0 + rloc;
        float4 h[8];
        if (r < N_NODES) {
            const float4* hp = (const float4*)(H + (size_t)r * DIN + sub * 32);
#pragma unroll
            for (int i = 0; i < 8; ++i) h[i] = hp[i];
        } else {
#pragma unroll
            for (int i = 0; i < 8; ++i) h[i] = make_float4(0.f, 0.f, 0.f, 0.f);
        }
        float ss = 0.f;
#pragma unroll
        for (int i = 0; i < 8; ++i)
            ss += h[i].x * h[i].x + h[i].y * h[i].y + h[i].z * h[i].z + h[i].w * h[i].w;
        ss += __shfl_xor(ss, 1, 64);
        ss += __shfl_xor(ss, 2, 64);                 // sum over the row's 4 threads
        const float inv = 1.0f / fmaxf(sqrtf(ss), 1e-12f);

        const float4* scp = (const float4*)(sc + sub * 32);
        const float4* shp = (const float4*)(sh + sub * 32);
#pragma unroll
        for (int i = 0; i < 8; ++i) {
            const float4 s4 = scp[i], b4 = shp[i];
            const float e0 = h[i].x * inv * s4.x + b4.x;
            const float e1 = h[i].y * inv * s4.y + b4.y;
            const float e2 = h[i].z * inv * s4.z + b4.z;
            const float e3 = h[i].w * inv * s4.w + b4.w;
            const unsigned u0 = (unsigned short)f2bf(e0) | ((unsigned)(unsigned short)f2bf(e1) << 16);
            const unsigned u1 = (unsigned short)f2bf(e2) | ((unsigned)(unsigned short)f2bf(e3) << 16);
            *(uint2*)&A_s[rloc][sub * 32 + i * 4] = make_uint2(u0, u1);
        }
    }
    // ---- stage B: copy prepped W^T bf16 into LDS ----
    {
        const int n = t >> 2, koff = (t & 3) * 32;
        const uint4* src = (const uint4*)(Wt + n * DIN + koff);
#pragma unroll
        for (int i = 0; i < 4; ++i)
            *(uint4*)&B_s[n][koff + i * 8] = src[i];
    }
    __syncthreads();

    // ---- MFMA: wave wv -> rows [wv*16, wv*16+16), all 64 cols ----
    const int ml = l & 15, q = l >> 4;
    f32x4 c0, c1, c2, c3;
    {
        const float b0 = bias[ml],      b1 = bias[16 + ml];
        const float b2 = bias[32 + ml], b3 = bias[48 + ml];
        c0 = f32x4{b0, b0, b0, b0};
        c1 = f32x4{b1, b1, b1, b1};
        c2 = f32x4{b2, b2, b2, b2};
        c3 = f32x4{b3, b3, b3, b3};
    }
#pragma unroll
    for (int k0 = 0; k0 < 4; ++k0) {
        const short8 a  = *(const short8*)&A_s[wv * 16 + ml][k0 * 32 + q * 8];
        const short8 b0 = *(const short8*)&B_s[ml][k0 * 32 + q * 8];
        const short8 b1 = *(const short8*)&B_s[16 + ml][k0 * 32 + q * 8];
        const short8 b2 = *(const short8*)&B_s[32 + ml][k0 * 32 + q * 8];
        const short8 b3 = *(const short8*)&B_s[48 + ml][k0 * 32 + q * 8];
        c0 = __builtin_amdgcn_mfma_f32_16x16x32_bf16(a, b0, c0, 0, 0, 0);
        c1 = __builtin_amdgcn_mfma_f32_16x16x32_bf16(a, b1, c1, 0, 0, 0);
        c2 = __builtin_amdgcn_mfma_f32_16x16x32_bf16(a, b2, c2, 0, 0, 0);
        c3 = __builtin_amdgcn_mfma_f32_16x16x32_bf16(a, b3, c3, 0, 0, 0);
    }
    // C/D layout: col = l&15, row = (l>>4)*4 + reg   [m89-verified]
#pragma unroll
    for (int i = 0; i < 4; ++i) {
        const int row = R0 + wv * 16 + q * 4 + i;
        if (row < N_NODES) {
            float* xr = X + (size_t)row * DOUT;
            xr[ml]      = c0[i];
            xr[16 + ml] = c1[i];
            xr[32 + ml] = c2[i];
            xr[48 + ml] = c3[i];
        }
    }
}

// ---------------- K2: bucket histogram (196 bins) via LDS -------------------
__global__ __launch_bounds__(1024) void k_bhist(
    const int* __restrict__ rows, int* __restrict__ hist)
{
    __shared__ int lh[NBUK];
    const int t = threadIdx.x;
    if (t < NBUK) lh[t] = 0;
    __syncthreads();
    const int e0 = blockIdx.x * 8192;
#pragma unroll
    for (int k = 0; k < 8; ++k) {
        const int e = e0 + k * 1024 + t;
        if (e < E_EDGES) atomicAdd(&lh[rows[e] >> 8], 1);
    }
    __syncthreads();
    if (t < NBUK) {
        const int c = lh[t];
        if (c) atomicAdd(&hist[t], c);
    }
}

// ---------------- K3: scan 196 bucket counts (1 block) ----------------------
__global__ __launch_bounds__(256) void k_bscan(
    const int* __restrict__ hist, int* __restrict__ gstart, int* __restrict__ gcursor)
{
    __shared__ int scn[256];
    const int t = threadIdx.x;
    const int v = (t < NBUK) ? hist[t] : 0;
    scn[t] = v;
    __syncthreads();
    for (int o = 1; o < 256; o <<= 1) {
        const int u = (t >= o) ? scn[t - o] : 0;
        __syncthreads();
        scn[t] += u;
        __syncthreads();
    }
    const int ex = scn[t] - v;
    if (t < NBUK) { gstart[t] = ex; gcursor[t] = ex; }
    if (t == NBUK - 1) gstart[NBUK] = ex + v;   // == E
}

// ---------------- K4: pass A — LDS-staged scatter into bucket runs ----------
// pack: col(16b) | (row&255)<<16 | (row>>8)<<24
__global__ __launch_bounds__(256) void k_passA(
    const int* __restrict__ rows, const int* __restrict__ cols,
    const float* __restrict__ vals, int* __restrict__ gcursor,
    uint2* __restrict__ mid)
{
    __shared__ int lhist[NBUK], lstart[NBUK], lcur[NBUK], gbase[NBUK];
    __shared__ int scn[256];
    __shared__ uint2 lbin[CHUNK];
    const int t = threadIdx.x;
    const int e0 = blockIdx.x * CHUNK;
    const int nC = min(CHUNK, E_EDGES - e0);

    if (t < NBUK) lhist[t] = 0;
    __syncthreads();

    uint2 pr[16];
#pragma unroll
    for (int k = 0; k < 16; ++k) {
        const int e = e0 + k * 256 + t;
        if (e < E_EDGES) {
            const int r = rows[e];
            const unsigned pk = (unsigned)cols[e] | ((unsigned)(r & 255) << 16)
                              | ((unsigned)(r >> 8) << 24);
            pr[k] = make_uint2(__float_as_uint(vals[e]), pk);
            atomicAdd(&lhist[r >> 8], 1);
        } else {
            pr[k] = make_uint2(0u, 0xFFFFFFFFu);
        }
    }
    __syncthreads();

    const int v = (t < NBUK) ? lhist[t] : 0;
    scn[t] = v;
    __syncthreads();
    for (int o = 1; o < 256; o <<= 1) {
        const int u = (t >= o) ? scn[t - o] : 0;
        __syncthreads();
        scn[t] += u;
        __syncthreads();
    }
    if (t < NBUK) {
        const int ex = scn[t] - v;
        lstart[t] = ex;
        lcur[t] = ex;
        gbase[t] = v ? atomicAdd(&gcursor[t], v) : 0;
    }
    __syncthreads();

#pragma unroll
    for (int k = 0; k < 16; ++k) {
        const unsigned pk = pr[k].y;
        if (pk != 0xFFFFFFFFu) {
            const int b = pk >> 24;
            const int pos = atomicAdd(&lcur[b], 1);
            lbin[pos] = pr[k];
        }
    }
    __syncthreads();

    for (int i = t; i < nC; i += 256) {
        const uint2 p = lbin[i];
        const int b = p.y >> 24;
        mid[gbase[b] + (i - lstart[b])] = p;
    }
}

// ---------------- K5: pass B — exact CSR within each bucket -----------------
__global__ __launch_bounds__(256) void k_passB(
    const int* __restrict__ gstart, const uint2* __restrict__ mid,
    uint2* __restrict__ ev, int* __restrict__ startRow)
{
    __shared__ int lhist[256], scn[256], lcur[256];
    const int t = threadIdx.x;
    const int b = blockIdx.x;
    const int s = gstart[b], e2 = gstart[b + 1];

    lhist[t] = 0;
    __syncthreads();
    for (int i = s + t; i < e2; i += 256)
        atomicAdd(&lhist[(mid[i].y >> 16) & 255], 1);
    __syncthreads();

    const int v = lhist[t];
    scn[t] = v;
    __syncthreads();
    for (int o = 1; o < 256; o <<= 1) {
        const int u = (t >= o) ? scn[t - o] : 0;
        __syncthreads();
        scn[t] += u;
        __syncthreads();
    }
    const int ex = scn[t] - v;
    lcur[t] = ex;
    const int gr = b * 256 + t;
    if (gr <= N_NODES) startRow[gr] = s + ex;
    __syncthreads();

    for (int i = s + t; i < e2; i += 256) {
        const uint2 p = mid[i];
        const int r8 = (p.y >> 16) & 255;
        const int pos = atomicAdd(&lcur[r8], 1);
        ev[s + pos] = make_uint2(p.x, p.y & 0xFFFFu);
    }
}

// ---------------- K6: SpMM + LeakyReLU — scalar-pipe edge broadcast ---------
// wave per row; edge list read via wave-uniform (SGPR) addresses -> s_load;
// X gather is one coalesced 256B VMEM per edge; val is an SGPR FMA operand.
__global__ __launch_bounds__(256) void k_spmm(
    const int* __restrict__ start, const uint2* __restrict__ ev,
    const float* __restrict__ X, float* __restrict__ out)
{
    const int lane = threadIdx.x & 63;
    const int row  = blockIdx.x * 4 + (threadIdx.x >> 6);
    if (row >= N_NODES) return;
    const int s  = __builtin_amdgcn_readfirstlane(start[row]);
    const int e2 = __builtin_amdgcn_readfirstlane(start[row + 1]);
    float acc = 0.f;
    int c = s;
    for (; c + 3 < e2; c += 4) {
        const uint2 p0 = ev[c],     p1 = ev[c + 1];
        const uint2 p2 = ev[c + 2], p3 = ev[c + 3];
        const float x0 = X[(int)p0.y * DOUT + lane];
        const float x1 = X[(int)p1.y * DOUT + lane];
        const float x2 = X[(int)p2.y * DOUT + lane];
        const float x3 = X[(int)p3.y * DOUT + lane];
        acc = fmaf(__uint_as_float(p0.x), x0, acc);
        acc = fmaf(__uint_as_float(p1.x), x1, acc);
        acc = fmaf(__uint_as_float(p2.x), x2, acc);
        acc = fmaf(__uint_as_float(p3.x), x3, acc);
    }
    for (; c < e2; ++c) {
        const uint2 p = ev[c];
        acc = fmaf(__uint_as_float(p.x), X[(int)p.y * DOUT + lane], acc);
    }
    out[(size_t)row * DOUT + lane] = (acc >= 0.f) ? acc : 0.01f * acc;
}

extern "C" void kernel_launch(void* const* d_in, const int* in_sizes, int n_in,
                              void* d_out, int out_size, void* d_ws, size_t ws_size,
                              hipStream_t stream)
{
    const float* H     = (const float*)d_in[0];
    const int*   rows  = (const int*)  d_in[1];
    const int*   cols  = (const int*)  d_in[2];
    const float* vals  = (const float*)d_in[3];
    const float* gamma = (const float*)d_in[4];
    const float* beta  = (const float*)d_in[5];
    const float* mean  = (const float*)d_in[6];
    const float* var   = (const float*)d_in[7];
    const float* W     = (const float*)d_in[8];
    const float* bias  = (const float*)d_in[9];
    float* out = (float*)d_out;

    char* ws = (char*)d_ws;
    float*          X        = (float*)(ws);                 // 12,800,000 B
    int*            hist     = (int*)  (ws + 12800000);      //        784 B
    int*            gstart   = (int*)  (ws + 12800800);      //        788 B
    int*            gcursor  = (int*)  (ws + 12801600);      //        784 B
    int*            startRow = (int*)  (ws + 12802400);      //    200,004 B
    uint2*          mid      = (uint2*)(ws + 13002416);      //  6,400,000 B
    uint2*          ev       = (uint2*)(ws + 19402416);      //  6,400,000 B
    unsigned short* Wt       = (unsigned short*)(ws + 25802416); // 16,384 B
    float*          sc       = (float*)(ws + 25818800);      //        512 B
    float*          sh       = (float*)(ws + 25819312);      //        512 B

    hipMemsetAsync(hist, 0, NBUK * sizeof(int), stream);

    k_prep<<<32, 256, 0, stream>>>(W, gamma, beta, mean, var, Wt, sc, sh);
    k_x<<<(N_NODES + 63) / 64, 256, 0, stream>>>(H, sc, sh, Wt, bias, X);
    k_bhist<<<(E_EDGES + 8191) / 8192, 1024, 0, stream>>>(rows, hist);
    k_bscan<<<1, 256, 0, stream>>>(hist, gstart, gcursor);
    k_passA<<<NBLKA, 256, 0, stream>>>(rows, cols, vals, gcursor, mid);
    k_passB<<<NBUK, 256, 0, stream>>>(gstart, mid, ev, startRow);
    k_spmm<<<(N_NODES + 3) / 4, 256, 0, stream>>>(startRow, ev, X, out);
}